// Round 4
// baseline (186.608 us; speedup 1.0000x reference)
//
#include <hip/hip_runtime.h>

// Model: generalized multinomial clique objective over 2- and 3-simplices.
// out = 2*obj2 + 4*obj3 where
//   obj2 = sum_edges (1 - 0.5 * p.q)
//   obj3 = sum_tris  (2 - p.q - p.r - q.r + (4/3) * sum_a p_a q_a r_a)
// with P = row-softmax of the scattered node-parameter matrix (n_L == 4).
//
// R1: removed same-cache-line atomics (were ~17 cyc/atomic serialized).
// R2/R3: block partials + fused edge/tri kernel; gather is TA-bound
//        (64 random lanes -> 64 cache lines per wave-gather, ~11 us floor).
// R4: fold the final reduction into the gather kernel (last-block pattern,
//     counter zeroed by softmax_rows) -> one fewer launch. Total is now
//     dominated by the harness d_ws re-poison fills (~45 us each @ 75% HBM).

#define NL 4

__device__ __forceinline__ float dot4(float4 a, float4 b) {
    return a.x * b.x + a.y * b.y + a.z * b.z + a.w * b.w;
}

__global__ void softmax_rows(const float* __restrict__ trainable,
                             const float* __restrict__ fixedp,
                             const int* __restrict__ fixed_idx,
                             float* __restrict__ P,
                             unsigned* __restrict__ counter,
                             int n_fixed, int n_total) {
    int i = blockIdx.x * blockDim.x + threadIdx.x;
    if (i == 0) *counter = 0u;  // consumed by gather_reduce (next kernel on stream)
    if (i >= n_total) return;
    float4 v;
    int dst;
    if (i < n_fixed) {
        v = ((const float4*)fixedp)[i];
        dst = fixed_idx[i];
    } else {
        v = ((const float4*)trainable)[i - n_fixed];
        dst = i;  // trainable_indices = arange(n_fixed, n_V)
    }
    float m = fmaxf(fmaxf(v.x, v.y), fmaxf(v.z, v.w));
    float ex = __expf(v.x - m), ey = __expf(v.y - m);
    float ez = __expf(v.z - m), ew = __expf(v.w - m);
    float inv = 1.0f / (ex + ey + ez + ew);
    ((float4*)P)[dst] = make_float4(ex * inv, ey * inv, ez * inv, ew * inv);
}

// Fused gather-reduce. Blocks [0, nb2): 4 edges/thread. Blocks [nb2, nb2+nb3):
// 4 triples/thread. Block partials to distinct slots; the last block to finish
// (release-RMW counter) reduces all partials and writes the scalar output.
__global__ void gather_reduce(const int* __restrict__ s2, int S2, int nb2,
                              const int* __restrict__ s3, int S3, int nb3,
                              const float* __restrict__ P,
                              float* __restrict__ part2,
                              float* __restrict__ part3,
                              unsigned* __restrict__ counter,
                              float* __restrict__ out) {
    const float4* __restrict__ Pv = (const float4*)P;
    __shared__ float lds[12];
    __shared__ int is_last;
    int wid = threadIdx.x >> 6;

    if ((int)blockIdx.x < nb2) {
        int tid = blockIdx.x * blockDim.x + threadIdx.x;
        int base = tid * 4;
        float sum = 0.f;
        if (base + 4 <= S2) {
            const int4* s = (const int4*)s2;
            int4 a = s[tid * 2], b = s[tid * 2 + 1];
            float4 p0 = Pv[a.x], q0 = Pv[a.y];
            float4 p1 = Pv[a.z], q1 = Pv[a.w];
            float4 p2 = Pv[b.x], q2 = Pv[b.y];
            float4 p3 = Pv[b.z], q3 = Pv[b.w];
            sum = dot4(p0, q0) + dot4(p1, q1) + dot4(p2, q2) + dot4(p3, q3);
        } else {
            for (int e = base; e < S2; ++e)
                sum += dot4(Pv[s2[2 * e]], Pv[s2[2 * e + 1]]);
        }
        #pragma unroll
        for (int off = 32; off > 0; off >>= 1) sum += __shfl_down(sum, off, 64);
        if ((threadIdx.x & 63) == 0) lds[wid] = sum;
        __syncthreads();
        if (threadIdx.x == 0)
            part2[blockIdx.x] = lds[0] + lds[1] + lds[2] + lds[3];
    } else {
        int bb = blockIdx.x - nb2;
        int tid = bb * blockDim.x + threadIdx.x;
        int base = tid * 4;
        float s_uvw = 0.f, s_t = 0.f;
        if (base + 4 <= S3) {
            const int4* s = (const int4*)s3;
            int4 a = s[tid * 3], b = s[tid * 3 + 1], c = s[tid * 3 + 2];
            int i0[4] = {a.x, a.w, b.z, c.y};
            int i1[4] = {a.y, b.x, b.w, c.z};
            int i2[4] = {a.z, b.y, c.x, c.w};
            float4 pp[4], qq[4], rr[4];
            #pragma unroll
            for (int k = 0; k < 4; ++k) {
                pp[k] = Pv[i0[k]]; qq[k] = Pv[i1[k]]; rr[k] = Pv[i2[k]];
            }
            #pragma unroll
            for (int k = 0; k < 4; ++k) {
                float4 p = pp[k], q = qq[k], r = rr[k];
                s_uvw += dot4(p, q) + dot4(p, r) + dot4(q, r);
                s_t += p.x * q.x * r.x + p.y * q.y * r.y
                     + p.z * q.z * r.z + p.w * q.w * r.w;
            }
        } else {
            for (int e = base; e < S3; ++e) {
                float4 p = Pv[s3[3 * e]], q = Pv[s3[3 * e + 1]], r = Pv[s3[3 * e + 2]];
                s_uvw += dot4(p, q) + dot4(p, r) + dot4(q, r);
                s_t += p.x * q.x * r.x + p.y * q.y * r.y
                     + p.z * q.z * r.z + p.w * q.w * r.w;
            }
        }
        #pragma unroll
        for (int off = 32; off > 0; off >>= 1) {
            s_uvw += __shfl_down(s_uvw, off, 64);
            s_t   += __shfl_down(s_t,   off, 64);
        }
        if ((threadIdx.x & 63) == 0) { lds[wid] = s_uvw; lds[4 + wid] = s_t; }
        __syncthreads();
        if (threadIdx.x == 0) {
            part3[2 * bb]     = lds[0] + lds[1] + lds[2] + lds[3];
            part3[2 * bb + 1] = lds[4] + lds[5] + lds[6] + lds[7];
        }
    }

    // --- last-block final reduction (agent-scope release/acquire RMW) ---
    if (threadIdx.x == 0) {
        unsigned old = __hip_atomic_fetch_add(counter, 1u, __ATOMIC_ACQ_REL,
                                              __HIP_MEMORY_SCOPE_AGENT);
        is_last = (old == (unsigned)(nb2 + nb3 - 1)) ? 1 : 0;
    }
    __syncthreads();
    if (!is_last) return;

    float dot2 = 0.f, uvw = 0.f, t = 0.f;
    for (int i = threadIdx.x; i < nb2; i += 256) dot2 += part2[i];
    for (int i = threadIdx.x; i < nb3; i += 256) {
        uvw += part3[2 * i];
        t   += part3[2 * i + 1];
    }
    #pragma unroll
    for (int off = 32; off > 0; off >>= 1) {
        dot2 += __shfl_down(dot2, off, 64);
        uvw  += __shfl_down(uvw,  off, 64);
        t    += __shfl_down(t,    off, 64);
    }
    __syncthreads();  // lds[] reuse
    if ((threadIdx.x & 63) == 0) {
        lds[wid] = dot2; lds[4 + wid] = uvw; lds[8 + wid] = t;
    }
    __syncthreads();
    if (threadIdx.x == 0) {
        float D = lds[0] + lds[1] + lds[2] + lds[3];
        float U = lds[4] + lds[5] + lds[6] + lds[7];
        float T = lds[8] + lds[9] + lds[10] + lds[11];
        float obj2 = (float)S2 - 0.5f * D;
        float obj3 = 2.f * (float)S3 - U + (4.f / 3.f) * T;
        out[0] = 2.f * obj2 + 4.f * obj3;
    }
}

extern "C" void kernel_launch(void* const* d_in, const int* in_sizes, int n_in,
                              void* d_out, int out_size, void* d_ws, size_t ws_size,
                              hipStream_t stream) {
    const float* trainable = (const float*)d_in[0];
    const float* fixedp    = (const float*)d_in[1];
    const int*   fixed_idx = (const int*)d_in[2];
    const int*   s2        = (const int*)d_in[3];
    const int*   s3        = (const int*)d_in[4];

    int n_fixed = in_sizes[2];
    int n_L     = in_sizes[1] / n_fixed;   // == 4
    int n_train = in_sizes[0] / n_L;
    int n_V     = n_fixed + n_train;
    int S2      = in_sizes[3] / 2;
    int S3      = in_sizes[4] / 3;
    (void)n_L; (void)ws_size; (void)n_in; (void)out_size;

    float* P     = (float*)d_ws;                  // n_V * 4 floats
    float* part2 = P + (size_t)n_V * NL;
    int threads2 = (S2 + 3) / 4;
    int nb2      = (threads2 + 255) / 256;
    float* part3 = part2 + nb2;
    int threads3 = (S3 + 3) / 4;
    int nb3      = (threads3 + 255) / 256;
    unsigned* counter = (unsigned*)(part3 + 2 * (size_t)nb3);

    softmax_rows<<<(n_V + 255) / 256, 256, 0, stream>>>(
        trainable, fixedp, fixed_idx, P, counter, n_fixed, n_V);

    gather_reduce<<<nb2 + nb3, 256, 0, stream>>>(
        s2, S2, nb2, s3, S3, nb3, P, part2, part3, counter, (float*)d_out);
}

// Round 5
// 112.476 us; speedup vs baseline: 1.6591x; 1.6591x over previous
//
#include <hip/hip_runtime.h>

// Model: generalized multinomial clique objective over 2- and 3-simplices.
// out = 2*obj2 + 4*obj3 where
//   obj2 = sum_edges (1 - 0.5 * p.q)
//   obj3 = sum_tris  (2 - p.q - p.r - q.r + (4/3) * sum_a p_a q_a r_a)
// with P = row-softmax of the scattered node-parameter matrix (n_L == 4).
//
// R1: removed same-cache-line atomics (were serialized ~34 cyc each).
// R2/R3: block partials, fused edge+tri gather kernel, 4 items/thread.
// R4 (REVERTED): last-block pattern with agent-scope ACQ_REL RMW caused
//     per-block L2 invalidations across XCDs -> P evicted continuously ->
//     gather 10us -> 130us. Lesson: no device-scope fences in the hot path.
// R5 = R3 exactly: measured 111.6 us total = harness re-poison floor (~95us,
//     two 268MB 0xAA fills @75% HBM peak) + TA-divergence-bound gather
//     (~10us: 64 random lanes -> 64 cache lines per wave-gather).

#define NL 4

__device__ __forceinline__ float dot4(float4 a, float4 b) {
    return a.x * b.x + a.y * b.y + a.z * b.z + a.w * b.w;
}

__global__ void softmax_rows(const float* __restrict__ trainable,
                             const float* __restrict__ fixedp,
                             const int* __restrict__ fixed_idx,
                             float* __restrict__ P,
                             int n_fixed, int n_total) {
    int i = blockIdx.x * blockDim.x + threadIdx.x;
    if (i >= n_total) return;
    float4 v;
    int dst;
    if (i < n_fixed) {
        v = ((const float4*)fixedp)[i];
        dst = fixed_idx[i];
    } else {
        v = ((const float4*)trainable)[i - n_fixed];
        dst = i;  // trainable_indices = arange(n_fixed, n_V)
    }
    float m = fmaxf(fmaxf(v.x, v.y), fmaxf(v.z, v.w));
    float ex = __expf(v.x - m), ey = __expf(v.y - m);
    float ez = __expf(v.z - m), ew = __expf(v.w - m);
    float inv = 1.0f / (ex + ey + ez + ew);
    ((float4*)P)[dst] = make_float4(ex * inv, ey * inv, ez * inv, ew * inv);
}

// Fused gather-reduce. Blocks [0, nb2): 4 edges/thread. Blocks [nb2, nb2+nb3):
// 4 triples/thread. Block-level partials to distinct slots (no atomics).
__global__ void gather_reduce(const int* __restrict__ s2, int S2, int nb2,
                              const int* __restrict__ s3, int S3,
                              const float* __restrict__ P,
                              float* __restrict__ part2,
                              float* __restrict__ part3) {
    const float4* __restrict__ Pv = (const float4*)P;
    __shared__ float lds[8];
    int wid = threadIdx.x >> 6;

    if ((int)blockIdx.x < nb2) {
        int tid = blockIdx.x * blockDim.x + threadIdx.x;
        int base = tid * 4;
        float sum = 0.f;
        if (base + 4 <= S2) {
            const int4* s = (const int4*)s2;
            int4 a = s[tid * 2], b = s[tid * 2 + 1];
            float4 p0 = Pv[a.x], q0 = Pv[a.y];
            float4 p1 = Pv[a.z], q1 = Pv[a.w];
            float4 p2 = Pv[b.x], q2 = Pv[b.y];
            float4 p3 = Pv[b.z], q3 = Pv[b.w];
            sum = dot4(p0, q0) + dot4(p1, q1) + dot4(p2, q2) + dot4(p3, q3);
        } else {
            for (int e = base; e < S2; ++e)
                sum += dot4(Pv[s2[2 * e]], Pv[s2[2 * e + 1]]);
        }
        #pragma unroll
        for (int off = 32; off > 0; off >>= 1) sum += __shfl_down(sum, off, 64);
        if ((threadIdx.x & 63) == 0) lds[wid] = sum;
        __syncthreads();
        if (threadIdx.x == 0)
            part2[blockIdx.x] = lds[0] + lds[1] + lds[2] + lds[3];
    } else {
        int bb = blockIdx.x - nb2;
        int tid = bb * blockDim.x + threadIdx.x;
        int base = tid * 4;
        float s_uvw = 0.f, s_t = 0.f;
        if (base + 4 <= S3) {
            const int4* s = (const int4*)s3;
            int4 a = s[tid * 3], b = s[tid * 3 + 1], c = s[tid * 3 + 2];
            int i0[4] = {a.x, a.w, b.z, c.y};
            int i1[4] = {a.y, b.x, b.w, c.z};
            int i2[4] = {a.z, b.y, c.x, c.w};
            float4 pp[4], qq[4], rr[4];
            #pragma unroll
            for (int k = 0; k < 4; ++k) {
                pp[k] = Pv[i0[k]]; qq[k] = Pv[i1[k]]; rr[k] = Pv[i2[k]];
            }
            #pragma unroll
            for (int k = 0; k < 4; ++k) {
                float4 p = pp[k], q = qq[k], r = rr[k];
                s_uvw += dot4(p, q) + dot4(p, r) + dot4(q, r);
                s_t += p.x * q.x * r.x + p.y * q.y * r.y
                     + p.z * q.z * r.z + p.w * q.w * r.w;
            }
        } else {
            for (int e = base; e < S3; ++e) {
                float4 p = Pv[s3[3 * e]], q = Pv[s3[3 * e + 1]], r = Pv[s3[3 * e + 2]];
                s_uvw += dot4(p, q) + dot4(p, r) + dot4(q, r);
                s_t += p.x * q.x * r.x + p.y * q.y * r.y
                     + p.z * q.z * r.z + p.w * q.w * r.w;
            }
        }
        #pragma unroll
        for (int off = 32; off > 0; off >>= 1) {
            s_uvw += __shfl_down(s_uvw, off, 64);
            s_t   += __shfl_down(s_t,   off, 64);
        }
        if ((threadIdx.x & 63) == 0) { lds[wid] = s_uvw; lds[4 + wid] = s_t; }
        __syncthreads();
        if (threadIdx.x == 0) {
            part3[2 * bb]     = lds[0] + lds[1] + lds[2] + lds[3];
            part3[2 * bb + 1] = lds[4] + lds[5] + lds[6] + lds[7];
        }
    }
}

__global__ void final_combine(const float* __restrict__ part2, int nb2,
                              const float* __restrict__ part3, int nb3,
                              float* __restrict__ out, float S2f, float S3f) {
    float dot2 = 0.f, uvw = 0.f, t = 0.f;
    for (int i = threadIdx.x; i < nb2; i += 256) dot2 += part2[i];
    for (int i = threadIdx.x; i < nb3; i += 256) {
        uvw += part3[2 * i];
        t   += part3[2 * i + 1];
    }
    #pragma unroll
    for (int off = 32; off > 0; off >>= 1) {
        dot2 += __shfl_down(dot2, off, 64);
        uvw  += __shfl_down(uvw,  off, 64);
        t    += __shfl_down(t,    off, 64);
    }
    __shared__ float lds[12];
    int wid = threadIdx.x >> 6;
    if ((threadIdx.x & 63) == 0) {
        lds[wid] = dot2; lds[4 + wid] = uvw; lds[8 + wid] = t;
    }
    __syncthreads();
    if (threadIdx.x == 0) {
        float D = lds[0] + lds[1] + lds[2] + lds[3];
        float U = lds[4] + lds[5] + lds[6] + lds[7];
        float T = lds[8] + lds[9] + lds[10] + lds[11];
        float obj2 = S2f - 0.5f * D;
        float obj3 = 2.f * S3f - U + (4.f / 3.f) * T;
        out[0] = 2.f * obj2 + 4.f * obj3;
    }
}

extern "C" void kernel_launch(void* const* d_in, const int* in_sizes, int n_in,
                              void* d_out, int out_size, void* d_ws, size_t ws_size,
                              hipStream_t stream) {
    const float* trainable = (const float*)d_in[0];
    const float* fixedp    = (const float*)d_in[1];
    const int*   fixed_idx = (const int*)d_in[2];
    const int*   s2        = (const int*)d_in[3];
    const int*   s3        = (const int*)d_in[4];

    int n_fixed = in_sizes[2];
    int n_L     = in_sizes[1] / n_fixed;   // == 4
    int n_train = in_sizes[0] / n_L;
    int n_V     = n_fixed + n_train;
    int S2      = in_sizes[3] / 2;
    int S3      = in_sizes[4] / 3;
    (void)n_L; (void)ws_size; (void)n_in; (void)out_size;

    float* P     = (float*)d_ws;                  // n_V * 4 floats
    float* part2 = P + (size_t)n_V * NL;
    int threads2 = (S2 + 3) / 4;
    int nb2      = (threads2 + 255) / 256;
    float* part3 = part2 + nb2;
    int threads3 = (S3 + 3) / 4;
    int nb3      = (threads3 + 255) / 256;

    softmax_rows<<<(n_V + 255) / 256, 256, 0, stream>>>(
        trainable, fixedp, fixed_idx, P, n_fixed, n_V);

    gather_reduce<<<nb2 + nb3, 256, 0, stream>>>(s2, S2, nb2, s3, S3, P,
                                                 part2, part3);

    final_combine<<<1, 256, 0, stream>>>(part2, nb2, part3, nb3,
                                         (float*)d_out, (float)S2, (float)S3);
}